// Round 5
// baseline (96.245 us; speedup 1.0000x reference)
//
#include <hip/hip_runtime.h>

// Chamfer loss: x [B,N,D], y [B,M,D], D=3, fp32.
// dist[b,m,n] = ||x[b,n]-y[b,m]||^2
// row[b] = mean_n min_m dist ; col[b] = mean_m min_n dist
// out = mean_b max(row, col)
//
// R5: 2 dispatches, no memsets, no hot-path atomics.
//  K1: 2048 blocks (2 dir x 32 batch x 32 target-chunks), 256 thr, QPT=8.
//      Register-block 8 queries/thread (block covers all 2048 queries),
//      scan 64-target LDS chunk, write partial mins [seg][chunk][query].
//      NO min-wave launch bound: R4's (256,8) capped VGPR at 64 and likely
//      spilled / killed prefetch ILP. ~80-96 VGPR -> 6 waves/SIMD is fine.
//      Block 0 also zeroes the done-counter for K2.
//  K2: 512 blocks: min over 32 chunks per query, finish dist, block sums;
//      last-arriving block (device-scope counter) reduces 512 block sums
//      -> per-seg totals -> max(row,col) -> mean -> out.

#define BATCH   32
#define NPTS    2048
#define THREADS 256
#define QPT     8              // 256*8 = 2048 queries per block
#define TCH     32             // target chunks per (dir,batch)
#define TC      (NPTS / TCH)   // 64 targets per chunk
#define NSEG    (2 * BATCH)    // 64 segments
#define CBLK    8              // combine blocks per segment
#define NCOMB   (NSEG * CBLK)  // 512 combine blocks

__global__ __launch_bounds__(THREADS) void chamfer_min(
    const float* __restrict__ x, const float* __restrict__ y,
    float* __restrict__ part /* [NSEG][TCH][NPTS] */,
    unsigned* __restrict__ done)
{
    __shared__ float4 t4[TC];   // (tx,ty,tz, 0.5*||t||^2) — 1 KB

    const int blk   = blockIdx.x;      // 2048
    const int dir   = blk >> 10;
    const int r     = blk & 1023;
    const int b     = r >> 5;
    const int chunk = r & 31;

    if (blk == 0 && threadIdx.x == 0) *done = 0u;   // arm K2's counter

    const float* q = (dir == 0 ? x : y) + (size_t)b * NPTS * 3;
    const float* t = (dir == 0 ? y : x) + (size_t)b * NPTS * 3;

    // Stage this chunk's 64 targets with precomputed h = 0.5*||t||^2.
    if (threadIdx.x < TC) {
        int jj = chunk * TC + threadIdx.x;
        float tx = t[3 * jj + 0];
        float ty = t[3 * jj + 1];
        float tz = t[3 * jj + 2];
        t4[threadIdx.x] = make_float4(tx, ty, tz, 0.5f * (tx * tx + ty * ty + tz * tz));
    }

    // 8 query points per thread (covers all 2048 queries per block).
    float qx[QPT], qy[QPT], qz[QPT], mn[QPT];
#pragma unroll
    for (int k = 0; k < QPT; ++k) {
        int qi = threadIdx.x + k * THREADS;
        qx[k] = q[3 * qi + 0];
        qy[k] = q[3 * qi + 1];
        qz[k] = q[3 * qi + 2];
        mn[k] = 3.4e38f;
    }
    __syncthreads();

    // min over chunk targets of s = h_t - q.t  (dist = 2s + ||q||^2, monotone)
#pragma unroll 4
    for (int j = 0; j < TC; j += 2) {
        float4 a = t4[j];
        float4 c = t4[j + 1];
#pragma unroll
        for (int k = 0; k < QPT; ++k) {
            float s0 = fmaf(-qz[k], a.z, fmaf(-qy[k], a.y, fmaf(-qx[k], a.x, a.w)));
            float s1 = fmaf(-qz[k], c.z, fmaf(-qy[k], c.y, fmaf(-qx[k], c.x, c.w)));
            mn[k] = fminf(fminf(mn[k], s0), s1);   // v_min3_f32
        }
    }

    // Plain coalesced partial writes — no init, no atomics.
    float* pbase = part + ((size_t)(dir * BATCH + b) * TCH + chunk) * NPTS;
#pragma unroll
    for (int k = 0; k < QPT; ++k)
        pbase[threadIdx.x + k * THREADS] = mn[k];
}

__global__ __launch_bounds__(THREADS) void chamfer_combine(
    const float* __restrict__ x, const float* __restrict__ y,
    const float* __restrict__ part,
    float* __restrict__ blocksums /* [NCOMB] */,
    unsigned* __restrict__ done,
    float* __restrict__ out)
{
    __shared__ float wsum[THREADS / 64];
    __shared__ int flagLast;

    const int blk = blockIdx.x;        // 512 = NSEG * CBLK
    const int seg = blk >> 3;
    const int qc  = blk & 7;
    const int dir = seg >> 5;
    const int b   = seg & 31;
    const int qi  = qc * THREADS + threadIdx.x;

    // min over the 32 chunk partials (wave-coalesced strided loads)
    const float* p = part + (size_t)seg * TCH * NPTS + qi;
    float mn = p[0];
#pragma unroll
    for (int c = 1; c < TCH; ++c)
        mn = fminf(mn, p[(size_t)c * NPTS]);

    const float* q = (dir == 0 ? x : y) + (size_t)b * NPTS * 3 + 3 * qi;
    float qx = q[0], qy = q[1], qz = q[2];
    float d = fmaf(2.0f, mn, qx * qx + qy * qy + qz * qz);

    for (int off = 32; off > 0; off >>= 1)
        d += __shfl_down(d, off);
    if ((threadIdx.x & 63) == 0) wsum[threadIdx.x >> 6] = d;
    __syncthreads();

    if (threadIdx.x == 0) {
        float tot = wsum[0] + wsum[1] + wsum[2] + wsum[3];
        __hip_atomic_store(&blocksums[blk], tot, __ATOMIC_RELEASE,
                           __HIP_MEMORY_SCOPE_AGENT);
        unsigned old = __hip_atomic_fetch_add(done, 1u, __ATOMIC_ACQ_REL,
                                              __HIP_MEMORY_SCOPE_AGENT);
        flagLast = (old == (unsigned)(NCOMB - 1));
    }
    __syncthreads();
    if (!flagLast) return;

    // ---- last block: per-seg totals, max(row,col), mean ----
    if (threadIdx.x < 64) {
        const int lane = threadIdx.x;   // lane = seg
        float s = 0.0f;
#pragma unroll
        for (int i = 0; i < CBLK; ++i)
            s += __hip_atomic_load(&blocksums[lane * CBLK + i],
                                   __ATOMIC_ACQUIRE, __HIP_MEMORY_SCOPE_AGENT);
        // lane < 32: row(batch=lane) ; lane >= 32: col(batch=lane-32)
        float other = __shfl(s, lane + 32);
        float v = (lane < 32) ? fmaxf(s, other) * (1.0f / NPTS) : 0.0f;
        for (int off = 16; off > 0; off >>= 1)
            v += __shfl_down(v, off);
        if (lane == 0) out[0] = v * (1.0f / BATCH);
    }
}

extern "C" void kernel_launch(void* const* d_in, const int* in_sizes, int n_in,
                              void* d_out, int out_size, void* d_ws, size_t ws_size,
                              hipStream_t stream) {
    const float* x = (const float*)d_in[0];
    const float* y = (const float*)d_in[1];
    float* out = (float*)d_out;

    float*    part      = (float*)d_ws;                          // 16 MB
    float*    blocksums = part + (size_t)NSEG * TCH * NPTS;      // 2 KB
    unsigned* done      = (unsigned*)(blocksums + NCOMB);

    chamfer_min<<<2 * BATCH * TCH, THREADS, 0, stream>>>(x, y, part, done);
    chamfer_combine<<<NCOMB, THREADS, 0, stream>>>(x, y, part, blocksums, done, out);
}